// Round 1
// baseline (1408.398 us; speedup 1.0000x reference)
//
#include <hip/hip_runtime.h>
#include <math.h>

#define BB 16
#define NN 512
#define HH 128
#define EE 4
#define NSTEPS 5
#define ROWS (BB*NN)      // 8192
#define KDIM (NN*EE)      // 2048
#define YC (HH*EE*2)      // 1024

// ---------------------------------------------------------------------------
// Prep: permute W_in/W_out columns so edge_states becomes a plain GEMM output.
// Wp[k, io*512 + e*128 + hh] = W_io[k, hh*4 + e];  bp likewise for biases.
// ---------------------------------------------------------------------------
__global__ void prep_kernel(const float* __restrict__ W_in, const float* __restrict__ b_in,
                            const float* __restrict__ W_out, const float* __restrict__ b_out,
                            float* __restrict__ Wp, float* __restrict__ bp) {
    int idx = blockIdx.x * 256 + threadIdx.x;   // over 128*1024
    if (idx >= HH * YC) return;
    int k = idx / YC;
    int c = idx - k * YC;
    int io = c >> 9;
    int cc = c & 511;
    int e  = cc >> 7;
    int hh = cc & 127;
    const float* W = io ? W_out : W_in;
    Wp[idx] = W[k * 512 + hh * 4 + e];
    if (k == 0) {
        const float* bb = io ? b_out : b_in;
        bp[c] = bb[hh * 4 + e];
    }
}

// ---------------------------------------------------------------------------
// GEMM A: Yp(8192x1024) = h(8192x128) @ Wp(128x1024) + bp
// 64x128 tile per block, 256 threads, each 4x8. K staged in chunks of 32.
// ---------------------------------------------------------------------------
__global__ __launch_bounds__(256) void gemm_x_w(const float* __restrict__ hcur,
        const float* __restrict__ Wp, const float* __restrict__ bp,
        float* __restrict__ Yp) {
    __shared__ float ht[64][33];
    __shared__ float wt[32][132];
    const int tid  = threadIdx.x;
    const int row0 = blockIdx.x * 64;   // 128 row tiles
    const int col0 = blockIdx.y * 128;  // 8 col tiles
    const int tx = tid & 15;            // cols tx*8..+8
    const int ty = tid >> 4;            // rows ty*4..+4
    float acc[4][8];
    #pragma unroll
    for (int j = 0; j < 8; j++) {
        float b = bp[col0 + tx * 8 + j];
        #pragma unroll
        for (int i = 0; i < 4; i++) acc[i][j] = b;
    }
    for (int kc = 0; kc < HH; kc += 32) {
        #pragma unroll
        for (int l = 0; l < 2; l++) {               // 64x32 h tile
            int f = tid + l * 256;                  // float4 index
            int r = f >> 3;
            int kk = (f & 7) << 2;
            float4 v = *(const float4*)(hcur + (size_t)(row0 + r) * HH + kc + kk);
            ht[r][kk + 0] = v.x; ht[r][kk + 1] = v.y; ht[r][kk + 2] = v.z; ht[r][kk + 3] = v.w;
        }
        #pragma unroll
        for (int l = 0; l < 4; l++) {               // 32x128 W tile
            int f = tid + l * 256;
            int kk = f >> 5;
            int c = (f & 31) << 2;
            float4 v = *(const float4*)(Wp + (size_t)(kc + kk) * YC + col0 + c);
            *(float4*)&wt[kk][c] = v;
        }
        __syncthreads();
        #pragma unroll
        for (int kk = 0; kk < 32; kk++) {
            float av[4];
            #pragma unroll
            for (int i = 0; i < 4; i++) av[i] = ht[ty * 4 + i][kk];
            float4 w0 = *(const float4*)&wt[kk][tx * 8];
            float4 w1 = *(const float4*)&wt[kk][tx * 8 + 4];
            float wv[8] = {w0.x, w0.y, w0.z, w0.w, w1.x, w1.y, w1.z, w1.w};
            #pragma unroll
            for (int i = 0; i < 4; i++)
                #pragma unroll
                for (int j = 0; j < 8; j++) acc[i][j] += av[i] * wv[j];
        }
        __syncthreads();
    }
    #pragma unroll
    for (int i = 0; i < 4; i++) {
        float* dst = Yp + (size_t)(row0 + ty * 4 + i) * YC + col0 + tx * 8;
        *(float4*)dst       = make_float4(acc[i][0], acc[i][1], acc[i][2], acc[i][3]);
        *(float4*)(dst + 4) = make_float4(acc[i][4], acc[i][5], acc[i][6], acc[i][7]);
    }
}

// ---------------------------------------------------------------------------
// GEMM B (the einsum): A_io[b](512x128) = M_io[b](512x2048) @ S_io[b](2048x128)
// S is read out of Yp with k = e*512 + n' decomposition (coalesced: rows of Yp).
// 64x64 tile per block, 256 threads, each 4x4. Grid 8x2x32 = 512 blocks.
// ---------------------------------------------------------------------------
__global__ __launch_bounds__(256) void gemm_msg(const float* __restrict__ m,
        const float* __restrict__ Yp, float* __restrict__ Ain, float* __restrict__ Aout) {
    __shared__ float Mt[64][33];
    __shared__ float St[32][68];
    const int tid = threadIdx.x;
    const int n0   = blockIdx.x * 64;   // 8 row tiles
    const int col0 = blockIdx.y * 64;   // 2 col tiles
    const int bz = blockIdx.z;          // b*2 + io
    const int b  = bz >> 1;
    const int io = bz & 1;
    const int tx = tid & 15;            // cols tx*4..+4
    const int ty = tid >> 4;            // rows ty*4..+4
    const float* Mbase = m + (size_t)b * NN * (2 * KDIM) + (size_t)io * KDIM;
    const float* Sbase = Yp + (size_t)b * NN * YC + io * 512;
    float acc[4][4] = {};
    for (int kc = 0; kc < KDIM; kc += 32) {
        int e  = kc >> 9;
        int nb = kc & 511;
        #pragma unroll
        for (int l = 0; l < 2; l++) {               // 64x32 M tile
            int f = tid + l * 256;
            int r = f >> 3;
            int kk = (f & 7) << 2;
            float4 v = *(const float4*)(Mbase + (size_t)(n0 + r) * (2 * KDIM) + kc + kk);
            Mt[r][kk + 0] = v.x; Mt[r][kk + 1] = v.y; Mt[r][kk + 2] = v.z; Mt[r][kk + 3] = v.w;
        }
        #pragma unroll
        for (int l = 0; l < 2; l++) {               // 32x64 S tile
            int f = tid + l * 256;
            int kk = f >> 4;
            int c = (f & 15) << 2;
            float4 v = *(const float4*)(Sbase + (size_t)(nb + kk) * YC + e * 128 + col0 + c);
            *(float4*)&St[kk][c] = v;
        }
        __syncthreads();
        #pragma unroll
        for (int kk = 0; kk < 32; kk++) {
            float av[4];
            #pragma unroll
            for (int i = 0; i < 4; i++) av[i] = Mt[ty * 4 + i][kk];
            float4 w = *(const float4*)&St[kk][tx * 4];
            float wv[4] = {w.x, w.y, w.z, w.w};
            #pragma unroll
            for (int i = 0; i < 4; i++)
                #pragma unroll
                for (int j = 0; j < 4; j++) acc[i][j] += av[i] * wv[j];
        }
        __syncthreads();
    }
    float* Abase = (io ? Aout : Ain) + (size_t)(b * NN + n0) * HH + col0;
    #pragma unroll
    for (int i = 0; i < 4; i++) {
        *(float4*)(Abase + (size_t)(ty * 4 + i) * HH + tx * 4) =
            make_float4(acc[i][0], acc[i][1], acc[i][2], acc[i][3]);
    }
}

// ---------------------------------------------------------------------------
// Gate kernel: GRU-style update for 16 rows per block (256 threads).
// cat = [a_in, a_out, h] (384); z,r = sigmoid(cat@W); joint 3rd block = r*h;
// h_hat = tanh(joint@W_t); h' = (1-z)h + z*h_hat.
// Thread (rg,hh) handles 8 rows x 1 output channel; W read once per block/k.
// ---------------------------------------------------------------------------
__global__ __launch_bounds__(256) void gate_kernel(
        const float* __restrict__ Ain, const float* __restrict__ Aout,
        const float* __restrict__ hcur,
        const float* __restrict__ W_z, const float* __restrict__ b_z,
        const float* __restrict__ W_r, const float* __restrict__ b_r,
        const float* __restrict__ W_t, const float* __restrict__ b_t,
        float* __restrict__ hnxt) {
    __shared__ float cat[16][385];
    const int tid = threadIdx.x;
    const int row0 = blockIdx.x * 16;   // 512 blocks
    for (int i = tid; i < 16 * 384; i += 256) {
        int r = i / 384;
        int c = i - r * 384;
        int grow = row0 + r;
        float v;
        if (c < 128)      v = Ain[(size_t)grow * HH + c];
        else if (c < 256) v = Aout[(size_t)grow * HH + c - 128];
        else              v = hcur[(size_t)grow * HH + c - 256];
        cat[r][c] = v;
    }
    __syncthreads();
    const int hh = tid & 127;
    const int rg = tid >> 7;
    float accz[8] = {}, accr[8] = {};
    for (int k = 0; k < 384; k++) {
        float wz = W_z[k * HH + hh];
        float wr = W_r[k * HH + hh];
        #pragma unroll
        for (int q = 0; q < 8; q++) {
            float cv = cat[rg * 8 + q][k];
            accz[q] += cv * wz;
            accr[q] += cv * wr;
        }
    }
    float hv[8], zv[8];
    #pragma unroll
    for (int q = 0; q < 8; q++) hv[q] = cat[rg * 8 + q][256 + hh];
    float bz = b_z[hh], br = b_r[hh];
    __syncthreads();   // all gate reads of cat done
    #pragma unroll
    for (int q = 0; q < 8; q++) {
        zv[q] = 1.0f / (1.0f + expf(-(accz[q] + bz)));
        float rv = 1.0f / (1.0f + expf(-(accr[q] + br)));
        cat[rg * 8 + q][256 + hh] = rv * hv[q];   // joint's 3rd block
    }
    __syncthreads();
    float acct[8] = {};
    for (int k = 0; k < 384; k++) {
        float wt = W_t[k * HH + hh];
        #pragma unroll
        for (int q = 0; q < 8; q++) acct[q] += cat[rg * 8 + q][k] * wt;
    }
    float bt = b_t[hh];
    #pragma unroll
    for (int q = 0; q < 8; q++) {
        float hhat = tanhf(acct[q] + bt);
        float hn = (1.0f - zv[q]) * hv[q] + zv[q] * hhat;
        hnxt[(size_t)(row0 + rg * 8 + q) * HH + hh] = hn;
    }
}

// ---------------------------------------------------------------------------
// Readout: feat = tanh([h, a] @ W1 + b1); out = feat@W2 + b2
// One row per block, 128 threads.
// ---------------------------------------------------------------------------
__global__ __launch_bounds__(128) void out_kernel(
        const float* __restrict__ hfin, const float* __restrict__ a,
        const float* __restrict__ W1, const float* __restrict__ b1,
        const float* __restrict__ W2, const float* __restrict__ b2,
        float* __restrict__ out) {
    __shared__ float hrow[129];
    __shared__ float red[2];
    const int tid = threadIdx.x;
    const int grow = blockIdx.x;
    hrow[tid] = hfin[(size_t)grow * HH + tid];
    if (tid == 0) hrow[128] = a[grow];
    __syncthreads();
    float acc = b1[tid];
    for (int k = 0; k < 129; k++) acc += hrow[k] * W1[k * HH + tid];
    float feat = tanhf(acc);
    float p = feat * W2[tid];
    #pragma unroll
    for (int off = 32; off > 0; off >>= 1) p += __shfl_down(p, off, 64);
    if ((tid & 63) == 0) red[tid >> 6] = p;
    __syncthreads();
    if (tid == 0) out[grow] = red[0] + red[1] + b2[0];
}

// ---------------------------------------------------------------------------
extern "C" void kernel_launch(void* const* d_in, const int* in_sizes, int n_in,
                              void* d_out, int out_size, void* d_ws, size_t ws_size,
                              hipStream_t stream) {
    const float* x    = (const float*)d_in[0];
    const float* a    = (const float*)d_in[1];
    const float* m    = (const float*)d_in[2];
    const float* W_in = (const float*)d_in[3];
    const float* b_in = (const float*)d_in[4];
    const float* W_out= (const float*)d_in[5];
    const float* b_out= (const float*)d_in[6];
    const float* W_z  = (const float*)d_in[7];
    const float* b_z  = (const float*)d_in[8];
    const float* W_r  = (const float*)d_in[9];
    const float* b_r  = (const float*)d_in[10];
    const float* W_t  = (const float*)d_in[11];
    const float* b_t  = (const float*)d_in[12];
    const float* W1   = (const float*)d_in[13];
    const float* b1   = (const float*)d_in[14];
    const float* W2   = (const float*)d_in[15];
    const float* b2   = (const float*)d_in[16];
    float* out = (float*)d_out;

    float* ws = (float*)d_ws;
    float* Wp = ws;                  // 128*1024        = 131072
    float* bp = Wp + 131072;         // 1024
    float* hA = bp + 1024;           // 8192*128        = 1048576
    float* hB = hA + 1048576;        // 1048576
    float* Yp = hB + 1048576;        // 8192*1024       = 8388608
    float* Ain  = Yp + 8388608;      // 1048576
    float* Aout = Ain + 1048576;     // 1048576  (total ~50.9 MB)

    prep_kernel<<<512, 256, 0, stream>>>(W_in, b_in, W_out, b_out, Wp, bp);
    hipMemcpyAsync(hA, x, (size_t)ROWS * HH * sizeof(float),
                   hipMemcpyDeviceToDevice, stream);

    float* cur = hA;
    float* nxt = hB;
    for (int s = 0; s < NSTEPS; s++) {
        gemm_x_w<<<dim3(128, 8), 256, 0, stream>>>(cur, Wp, bp, Yp);
        gemm_msg<<<dim3(8, 2, 32), 256, 0, stream>>>(m, Yp, Ain, Aout);
        gate_kernel<<<512, 256, 0, stream>>>(Ain, Aout, cur,
                                             W_z, b_z, W_r, b_r, W_t, b_t, nxt);
        float* t = cur; cur = nxt; nxt = t;
    }
    out_kernel<<<ROWS, 128, 0, stream>>>(cur, a, W1, b1, W2, b2, out);
}